// Round 7
// baseline (120.658 us; speedup 1.0000x reference)
//
#include <hip/hip_runtime.h>
#include <hip/hip_bf16.h>
#include <math.h>

// Problem constants (fixed by the reference).
#define B_  16
#define N_  16384
#define D_  64
#define K_  64
#define OUT_PER_B (K_ + 2*K_*D_)   // 8256
#define CHUNKS 64                  // 1024 blocks = EXACTLY 4 blocks/CU x 256 CU
#define NTILES (N_ / CHUNKS / 64)  // 4

// ws layout: per (b,chunk) partial record at offset (b*CHUNKS+chunk)*PART_STRIDE:
//   f32 qsum[64] | bf16 qx[64*64] | bf16 qx2[64*64]   (16640 B)
#define PART_STRIDE (64*4 + 2*4096*2)   // 16640 bytes
#define PART_TOTAL  ((size_t)B_ * CHUNKS * PART_STRIDE)   // 17,039,360 B
// prep region appended after partials:
#define W_OFF   PART_TOTAL            // 16 KB packed wfrag [(kt*4+op)*64+lane]*16B
#define C0_OFF  (PART_TOTAL + 16384)  // 64 f32

typedef float f32x4 __attribute__((ext_vector_type(4)));
typedef short short8 __attribute__((ext_vector_type(8)));

union U8 { short8 s8; unsigned int u[4]; };

__device__ __forceinline__ unsigned short f2bf(float f) {
    union { float f; unsigned int u; } v; v.f = f;
    unsigned int r = v.u + 0x7FFFu + ((v.u >> 16) & 1u);   // round-to-nearest-even
    return (unsigned short)(r >> 16);
}

// packed RNE f32x2 -> bf16x2 (v_cvt_pk_bf16_f32 on gfx950)
__device__ __forceinline__ unsigned int f2bf2(float lo, float hi) {
    __hip_bfloat162 h = __float22bfloat162_rn(make_float2(lo, hi));
    unsigned int u;
    __builtin_memcpy(&u, &h, 4);
    return u;
}

__device__ __forceinline__ float bf2f(unsigned short u) {
    unsigned int v = ((unsigned int)u) << 16;
    float f;
    __builtin_memcpy(&f, &v, 4);
    return f;
}

// Prep hoisted out of fv_main (R11). wfrag depends only on lane (identical for
// every wave of every block) -> compute ONCE here (16 KB) + c0s, store to ws.
__global__ __launch_bounds__(256) void fv_prep(const float* __restrict__ pi,
                                               const float* __restrict__ mu,
                                               const float* __restrict__ var,
                                               char* __restrict__ ws) {
    __shared__ float red[256];
    const int t = threadIdx.x;

    // c0 partial sums (exact replication of original summation order)
    {
        int k = t >> 2, pr = t & 3;
        float s = 0.0f;
        #pragma unroll
        for (int j = 0; j < 16; ++j) {
            int d = pr * 16 + j;
            float v = var[k * 64 + d];
            float m = mu[k * 64 + d];
            s += __logf(v) + m * m / v;
        }
        red[t] = s;
    }

    // wfrag for (lane = t&63, kt = t>>6): same per-element math as before.
    {
        const int lane = t & 63;
        const int kt   = t >> 6;
        const int r16  = lane & 15;
        const int q    = lane >> 4;
        const int k = 16 * kt + r16;
        const float* vr = var + k * 64 + 8 * q;
        const float* mr = mu  + k * 64 + 8 * q;
        float vv[16], mm[16];
        *(float4*)&vv[0]  = *(const float4*)(vr);
        *(float4*)&vv[4]  = *(const float4*)(vr + 4);
        *(float4*)&vv[8]  = *(const float4*)(vr + 32);
        *(float4*)&vv[12] = *(const float4*)(vr + 36);
        *(float4*)&mm[0]  = *(const float4*)(mr);
        *(float4*)&mm[4]  = *(const float4*)(mr + 4);
        *(float4*)&mm[8]  = *(const float4*)(mr + 32);
        *(float4*)&mm[12] = *(const float4*)(mr + 36);
        float iv[16];
        #pragma unroll
        for (int i = 0; i < 16; ++i) iv[i] = 1.0f / vv[i];
        U8 h0, h1, h2, h3;
        #pragma unroll
        for (int i = 0; i < 4; ++i) {
            h0.u[i] = f2bf2(-0.5f * iv[2*i],     -0.5f * iv[2*i + 1]);
            h1.u[i] = f2bf2(-0.5f * iv[8 + 2*i], -0.5f * iv[8 + 2*i + 1]);
            h2.u[i] = f2bf2(mm[2*i] * iv[2*i],   mm[2*i+1] * iv[2*i + 1]);
            h3.u[i] = f2bf2(mm[8+2*i] * iv[8+2*i], mm[8+2*i+1] * iv[8+2*i+1]);
        }
        short8* W = (short8*)(ws + W_OFF);
        W[(kt * 4 + 0) * 64 + lane] = h0.s8;
        W[(kt * 4 + 1) * 64 + lane] = h1.s8;
        W[(kt * 4 + 2) * 64 + lane] = h2.s8;
        W[(kt * 4 + 3) * 64 + lane] = h3.s8;
    }

    __syncthreads();
    if ((t & 3) == 0) {
        int k = t >> 2;
        float sum = red[4 * k] + red[4 * k + 1] + red[4 * k + 2] + red[4 * k + 3];
        // D*log(2*pi) = 117.6241322501981
        ((float*)(ws + C0_OFF))[k] = __logf(pi[k]) - 0.5f * (117.6241322502f + sum);
    }
}

// MFMA layouts (16x16x32 bf16, guide-verified):
//   A[m = lane&15][kk = (lane>>4)*8 + j]
//   B[kk = (lane>>4)*8 + j][n = lane&15]
//   C/D: col = lane&15, row = 4*(lane>>4) + reg
// R13 config kept verbatim (passing, no spill): (256,4), 1024 blocks = one
// packed round, vle issued post-softmax, tile loop unroll 1.
__global__ __launch_bounds__(256, 4) void fv_main(const float* __restrict__ x,
                                                  char* __restrict__ partials) {
    __shared__ __align__(16) unsigned short QtS[2][64 * 72];  // double-buffered Q^T[k][p]
    __shared__ __align__(16) unsigned short wfS[4 * 4 * 64 * 8];  // 16 KB A-fragments
    __shared__ float qsum_s[4][64];

    const int t    = threadIdx.x;
    const int w    = t >> 6;        // wave 0..3
    const int lane = t & 63;
    const int r16  = lane & 15;
    const int q    = lane >> 4;     // quad 0..3

    // ---- cooperative load of precomputed wfrag into LDS (16 KB, coalesced) ----
    {
        const float4* gw = (const float4*)(partials + W_OFF);
        float4* sw = (float4*)wfS;
        #pragma unroll
        for (int i = 0; i < 4; ++i) sw[i * 256 + t] = gw[i * 256 + t];
    }
    // c0 row constants straight from global (256 B, L2-broadcast)
    f32x4 c0v[4];
    {
        const float* c0g = (const float*)(partials + C0_OFF);
        #pragma unroll
        for (int kt = 0; kt < 4; ++kt)
            c0v[kt] = *(const f32x4*)&c0g[16 * kt + 4 * q];
    }

    const int bi    = blockIdx.y;
    const int chunk = blockIdx.x;
    const int ppb   = N_ / CHUNKS;
    const float* xb = x + ((size_t)bi * N_ + (size_t)chunk * ppb) * D_;

    f32x4 accX[4]  = {};       // Qx  : k rows, d col = 16w + r16
    f32x4 accX2[4] = {};       // Qx2
    float qsacc[4][4] = {};    // per-lane Q sums (ks: 16kt + 4q + rr)

    const int rowoff = (16 * w + r16) * D_ + 8 * q;   // phase-1 row base
    const int dcol   = 16 * w + r16;                  // phase-2 column

    const short8* wfp = (const short8*)wfS;   // [(kt*4+op)*64 + lane]

    __syncthreads();            // wfS ready

    #pragma unroll 1
    for (int tile = 0; tile < NTILES; ++tile) {
        const float* xt = xb + (size_t)tile * 64 * D_;

        // ---- row loads for CURRENT tile ----
        float4 va, vb, vc, vd;
        {
            const float* xr = xt + rowoff;
            va = *(const float4*)(xr);
            vb = *(const float4*)(xr + 4);
            vc = *(const float4*)(xr + 32);
            vd = *(const float4*)(xr + 36);
        }

        // ================= phase 1: S^T[k][p] =================
        U8 fxa, fxb, fx2a, fx2b;
        fxa.u[0]  = f2bf2(va.x, va.y);           fxa.u[1]  = f2bf2(va.z, va.w);
        fxa.u[2]  = f2bf2(vb.x, vb.y);           fxa.u[3]  = f2bf2(vb.z, vb.w);
        fxb.u[0]  = f2bf2(vc.x, vc.y);           fxb.u[1]  = f2bf2(vc.z, vc.w);
        fxb.u[2]  = f2bf2(vd.x, vd.y);           fxb.u[3]  = f2bf2(vd.z, vd.w);
        fx2a.u[0] = f2bf2(va.x*va.x, va.y*va.y); fx2a.u[1] = f2bf2(va.z*va.z, va.w*va.w);
        fx2a.u[2] = f2bf2(vb.x*vb.x, vb.y*vb.y); fx2a.u[3] = f2bf2(vb.z*vb.z, vb.w*vb.w);
        fx2b.u[0] = f2bf2(vc.x*vc.x, vc.y*vc.y); fx2b.u[1] = f2bf2(vc.z*vc.z, vc.w*vc.w);
        fx2b.u[2] = f2bf2(vd.x*vd.x, vd.y*vd.y); fx2b.u[3] = f2bf2(vd.z*vd.z, vd.w*vd.w);

        float sc[4][4];
        #pragma unroll
        for (int kt = 0; kt < 4; ++kt) {
            f32x4 a = c0v[kt];
            a = __builtin_amdgcn_mfma_f32_16x16x32_bf16(wfp[(kt*4+0)*64 + lane], fx2a.s8, a, 0, 0, 0);
            a = __builtin_amdgcn_mfma_f32_16x16x32_bf16(wfp[(kt*4+1)*64 + lane], fx2b.s8, a, 0, 0, 0);
            a = __builtin_amdgcn_mfma_f32_16x16x32_bf16(wfp[(kt*4+2)*64 + lane], fxa.s8,  a, 0, 0, 0);
            a = __builtin_amdgcn_mfma_f32_16x16x32_bf16(wfp[(kt*4+3)*64 + lane], fxb.s8,  a, 0, 0, 0);
            sc[kt][0] = a[0]; sc[kt][1] = a[1]; sc[kt][2] = a[2]; sc[kt][3] = a[3];
        }

        // ---- softmax over k: 16 in-lane values + lanes^16,^32 (same point p) ----
        float mx = sc[0][0];
        #pragma unroll
        for (int kt = 0; kt < 4; ++kt)
            #pragma unroll
            for (int rr = 0; rr < 4; ++rr) mx = fmaxf(mx, sc[kt][rr]);
        mx = fmaxf(mx, __shfl_xor(mx, 16));
        mx = fmaxf(mx, __shfl_xor(mx, 32));
        float z = 0.0f;
        #pragma unroll
        for (int kt = 0; kt < 4; ++kt)
            #pragma unroll
            for (int rr = 0; rr < 4; ++rr) {
                sc[kt][rr] = __expf(sc[kt][rr] - mx);
                z += sc[kt][rr];
            }
        z += __shfl_xor(z, 16);
        z += __shfl_xor(z, 32);
        float inv = 1.0f / z;

        // ---- phase-2 column loads: issued HERE (post-softmax, short live
        //      range); stay vmcnt-in-flight across the lgkmcnt-only barrier ----
        float vle[16];
        {
            const float* xc = xt + dcol;
            #pragma unroll
            for (int c = 0; c < 2; ++c)
                #pragma unroll
                for (int j = 0; j < 8; ++j)
                    vle[8 * c + j] = xc[(32 * c + 8 * q + j) * D_];
        }

        const int p = 16 * w + r16;
        unsigned short* Qb = QtS[tile & 1];
        #pragma unroll
        for (int kt = 0; kt < 4; ++kt) {
            #pragma unroll
            for (int rr = 0; rr < 4; rr += 2) {
                float q0 = sc[kt][rr] * inv;
                float q1 = sc[kt][rr + 1] * inv;
                qsacc[kt][rr]     += q0;
                qsacc[kt][rr + 1] += q1;
                unsigned int pk = f2bf2(q0, q1);
                Qb[(16 * kt + 4 * q + rr)     * 72 + p] = (unsigned short)pk;
                Qb[(16 * kt + 4 * q + rr + 1) * 72 + p] = (unsigned short)(pk >> 16);
            }
        }

        // barrier WITHOUT vmcnt(0) drain (LDS visibility only) — keeps loads in flight
        asm volatile("s_waitcnt lgkmcnt(0)\n\ts_barrier" ::: "memory");

        // ================= phase 2: Qx[k][d], Qx2[k][d] =================
        U8 fxp0, fxp1, fx2p0, fx2p1;
        #pragma unroll
        for (int i = 0; i < 4; ++i) {
            float a0 = vle[2 * i], a1 = vle[2 * i + 1];
            float b0 = vle[8 + 2 * i], b1 = vle[8 + 2 * i + 1];
            fxp0.u[i]  = f2bf2(a0, a1);
            fxp1.u[i]  = f2bf2(b0, b1);
            fx2p0.u[i] = f2bf2(a0 * a0, a1 * a1);
            fx2p1.u[i] = f2bf2(b0 * b0, b1 * b1);
        }
        #pragma unroll
        for (int kt = 0; kt < 4; ++kt) {
            const unsigned short* qr = &Qb[(16 * kt + r16) * 72 + 8 * q];
            short8 aq0 = *(const short8*)(const void*)(qr);
            short8 aq1 = *(const short8*)(const void*)(qr + 32);
            accX[kt]  = __builtin_amdgcn_mfma_f32_16x16x32_bf16(aq0, fxp0.s8,  accX[kt],  0, 0, 0);
            accX2[kt] = __builtin_amdgcn_mfma_f32_16x16x32_bf16(aq0, fx2p0.s8, accX2[kt], 0, 0, 0);
            accX[kt]  = __builtin_amdgcn_mfma_f32_16x16x32_bf16(aq1, fxp1.s8,  accX[kt],  0, 0, 0);
            accX2[kt] = __builtin_amdgcn_mfma_f32_16x16x32_bf16(aq1, fx2p1.s8, accX2[kt], 0, 0, 0);
        }
    }

    // ---- write partials: f32 qsum[64] | bf16 qx[4096] | bf16 qx2[4096] ----
    char* rec = partials + ((size_t)bi * CHUNKS + chunk) * PART_STRIDE;
    float* part_qs = (float*)rec;
    unsigned short* part_qx  = (unsigned short*)(rec + 256);
    unsigned short* part_qx2 = part_qx + 4096;
    #pragma unroll
    for (int kt = 0; kt < 4; ++kt)
        #pragma unroll
        for (int rr = 0; rr < 4; ++rr) {
            int k = 16 * kt + 4 * q + rr;
            part_qx [k * 64 + 16 * w + r16] = f2bf(accX[kt][rr]);
            part_qx2[k * 64 + 16 * w + r16] = f2bf(accX2[kt][rr]);
        }
    #pragma unroll
    for (int kt = 0; kt < 4; ++kt)
        #pragma unroll
        for (int rr = 0; rr < 4; ++rr) {
            float v = qsacc[kt][rr];
            v += __shfl_xor(v, 1);
            v += __shfl_xor(v, 2);
            v += __shfl_xor(v, 4);
            v += __shfl_xor(v, 8);
            if (r16 == 0) qsum_s[w][16 * kt + 4 * q + rr] = v;
        }
    __syncthreads();
    if (t < 64)
        part_qs[t] = qsum_s[0][t] + qsum_s[1][t] + qsum_s[2][t] + qsum_s[3][t];
}

// R14 finalize: vectorized + shuffle-tree. Old version: 48 scalar loads/thread
// (2-4 B each, 16.6 KB stride) = latency-bound, ~35-42 us (the hidden cost in
// every round's residual). New lane map: lane = cs(chunk-sub 0..7) x dg(d-octet
// 0..7); one short8 load per lane covers 8 chunks x 128 B = 1 KB per wave-instr.
// Per wave: 2 iters x 2 vector loads + qs = 6 load instrs (was 48), fully
// independent -> MLP covers L3 latency. Cross-chunk reduce: shfl_xor(8,16,32).
__global__ __launch_bounds__(256) void fv_finalize(const float* __restrict__ pi,
                                                   const float* __restrict__ mu,
                                                   const float* __restrict__ var,
                                                   const char* __restrict__ partials,
                                                   float* __restrict__ out) {
    const int bk   = blockIdx.x;
    const int b    = bk >> 6;
    const int k    = bk & 63;
    const int t    = threadIdx.x;
    const int cg   = t >> 6;            // wave: chunk-group of 16
    const int lane = t & 63;
    const int cs   = lane >> 3;         // chunk-sub 0..7
    const int dg   = lane & 7;          // d-octet 0..7

    const char* base = partials + (size_t)b * CHUNKS * PART_STRIDE;

    float qx[8]  = {};
    float qx2[8] = {};
    float qs = 0.0f;
    #pragma unroll
    for (int i = 0; i < 2; ++i) {
        const char* r = base + (size_t)(16 * cg + 8 * i + cs) * PART_STRIDE;
        short8 vx  = *(const short8*)(const void*)(r + 256 + k * 128 + dg * 16);
        short8 vx2 = *(const short8*)(const void*)(r + 256 + 8192 + k * 128 + dg * 16);
        if (dg == 0) qs += ((const float*)r)[k];
        #pragma unroll
        for (int j = 0; j < 8; ++j) {
            qx[j]  += bf2f((unsigned short)vx[j]);
            qx2[j] += bf2f((unsigned short)vx2[j]);
        }
    }

    // reduce across the 8 cs-lanes (masks 8,16,32); qs across the whole wave
    #pragma unroll
    for (int m = 8; m <= 32; m <<= 1) {
        #pragma unroll
        for (int j = 0; j < 8; ++j) {
            qx[j]  += __shfl_xor(qx[j],  m);
            qx2[j] += __shfl_xor(qx2[j], m);
        }
    }
    qs += __shfl_xor(qs, 1);
    qs += __shfl_xor(qs, 2);
    qs += __shfl_xor(qs, 4);
    qs += __shfl_xor(qs, 8);
    qs += __shfl_xor(qs, 16);
    qs += __shfl_xor(qs, 32);

    __shared__ float sQx[4][64];
    __shared__ float sQx2[4][64];
    __shared__ float sQs[4];
    if (cs == 0) {
        #pragma unroll
        for (int j = 0; j < 8; ++j) {
            sQx[cg][dg * 8 + j]  = qx[j];
            sQx2[cg][dg * 8 + j] = qx2[j];
        }
    }
    if (lane == 0) sQs[cg] = qs;
    __syncthreads();

    if (cg == 0) {
        const int d = lane;             // 64 lanes cover d = 0..63
        const float invN = 1.0f / (float)N_;
        float QX  = sQx[0][d]  + sQx[1][d]  + sQx[2][d]  + sQx[3][d];
        float QX2 = sQx2[0][d] + sQx2[1][d] + sQx2[2][d] + sQx2[3][d];
        float QS  = sQs[0] + sQs[1] + sQs[2] + sQs[3];
        float m = mu[k * 64 + d];
        float v = var[k * 64 + d];
        float* ob = out + (size_t)b * OUT_PER_B;
        if (d == 0) ob[k] = QS * invN - pi[k];
        ob[64 + k * 64 + d]        = (QX - QS * m) * invN;
        ob[64 + 4096 + k * 64 + d] = (-QX2 - QS * m * m + QS * v + 2.0f * QX * m) * invN;
    }
}

extern "C" void kernel_launch(void* const* d_in, const int* in_sizes, int n_in,
                              void* d_out, int out_size, void* d_ws, size_t ws_size,
                              hipStream_t stream) {
    const float* x   = (const float*)d_in[0];
    const float* pi  = (const float*)d_in[1];
    const float* mu  = (const float*)d_in[2];
    const float* var = (const float*)d_in[3];
    char* ws = (char*)d_ws;

    fv_prep<<<1, 256, 0, stream>>>(pi, mu, var, ws);
    fv_main<<<dim3(CHUNKS, B_), 256, 0, stream>>>(x, ws);
    fv_finalize<<<B_ * K_, 256, 0, stream>>>(pi, mu, var, ws, (float*)d_out);
}

// Round 8
// 119.853 us; speedup vs baseline: 1.0067x; 1.0067x over previous
//
#include <hip/hip_runtime.h>
#include <hip/hip_cooperative_groups.h>
#include <hip/hip_bf16.h>
#include <math.h>

namespace cg = cooperative_groups;

// Problem constants (fixed by the reference).
#define B_  16
#define N_  16384
#define D_  64
#define K_  64
#define OUT_PER_B (K_ + 2*K_*D_)   // 8256
#define CHUNKS 64                  // 1024 blocks = EXACTLY 4 blocks/CU x 256 CU
#define NTILES (N_ / CHUNKS / 64)  // 4

// ws layout: per (b,chunk) partial record at offset (b*CHUNKS+chunk)*PART_STRIDE:
//   f32 qsum[64] | bf16 qx[64*64] | bf16 qx2[64*64]   (16640 B)
#define PART_STRIDE (64*4 + 2*4096*2)   // 16640 bytes
#define PART_TOTAL  ((size_t)B_ * CHUNKS * PART_STRIDE)   // 17,039,360 B
// prep region appended after partials (fallback path only):
#define W_OFF   PART_TOTAL            // 16 KB packed wfrag [(kt*4+op)*64+lane]*16B
#define C0_OFF  (PART_TOTAL + 16384)  // 64 f32

typedef float f32x4 __attribute__((ext_vector_type(4)));
typedef short short8 __attribute__((ext_vector_type(8)));

union U8 { short8 s8; unsigned int u[4]; };

__device__ __forceinline__ unsigned short f2bf(float f) {
    union { float f; unsigned int u; } v; v.f = f;
    unsigned int r = v.u + 0x7FFFu + ((v.u >> 16) & 1u);   // round-to-nearest-even
    return (unsigned short)(r >> 16);
}

// packed RNE f32x2 -> bf16x2 (v_cvt_pk_bf16_f32 on gfx950)
__device__ __forceinline__ unsigned int f2bf2(float lo, float hi) {
    __hip_bfloat162 h = __float22bfloat162_rn(make_float2(lo, hi));
    unsigned int u;
    __builtin_memcpy(&u, &h, 4);
    return u;
}

__device__ __forceinline__ float bf2f(unsigned short u) {
    unsigned int v = ((unsigned int)u) << 16;
    float f;
    __builtin_memcpy(&f, &v, 4);
    return f;
}

// ============================================================================
// R15: single cooperative kernel. Rationale: R14 falsified the "finalize is
// slow" theory (vectorized finalize -> total unchanged). Accounting now says
// ~25-35 us of the 120 is inter-dispatch overhead of the 3-kernel pipeline.
// Fuse: in-block prep (LDS wfrag, 1x work per thread) + R13 main loop +
// threadfence + grid.sync() + R14 finalize body (block (b,k) = (by,bx) -- the
// 1024-block grid maps 1:1). LDS 37.1 KB, 4 blocks/CU holds co-residency.
// ============================================================================
__global__ __launch_bounds__(256, 4) void fv_fused(const float* __restrict__ x,
                                                   const float* __restrict__ pi,
                                                   const float* __restrict__ mu,
                                                   const float* __restrict__ var,
                                                   char* __restrict__ partials,
                                                   float* __restrict__ out) {
    __shared__ __align__(16) unsigned short QtS[2][64 * 72];      // 18432 B
    __shared__ __align__(16) unsigned short wfS[4 * 4 * 64 * 8];  // 16384 B
    __shared__ float qsum_s[4][64];                               // 1024 B (reused: sQx)
    __shared__ float red[256];                                    // 1024 B (reused: sQx2)
    __shared__ __align__(16) float c0s[64];                       // 256 B  (reused: sQs)

    const int t    = threadIdx.x;
    const int w    = t >> 6;        // wave 0..3
    const int lane = t & 63;
    const int r16  = lane & 15;
    const int q    = lane >> 4;     // quad 0..3

    // ==================== in-block prep ====================
    // c0 partial sums (exact replication of original summation order)
    {
        int k = t >> 2, pr = t & 3;
        float s = 0.0f;
        #pragma unroll
        for (int j = 0; j < 16; ++j) {
            int d = pr * 16 + j;
            float v = var[k * 64 + d];
            float m = mu[k * 64 + d];
            s += __logf(v) + m * m / v;
        }
        red[t] = s;
    }
    // wfrag: thread t covers (kt = t>>6, lane) -> 4 op-fragments into LDS
    {
        const int kt = t >> 6;
        const int k = 16 * kt + r16;
        const float* vr = var + k * 64 + 8 * q;
        const float* mr = mu  + k * 64 + 8 * q;
        float vv[16], mm[16];
        *(float4*)&vv[0]  = *(const float4*)(vr);
        *(float4*)&vv[4]  = *(const float4*)(vr + 4);
        *(float4*)&vv[8]  = *(const float4*)(vr + 32);
        *(float4*)&vv[12] = *(const float4*)(vr + 36);
        *(float4*)&mm[0]  = *(const float4*)(mr);
        *(float4*)&mm[4]  = *(const float4*)(mr + 4);
        *(float4*)&mm[8]  = *(const float4*)(mr + 32);
        *(float4*)&mm[12] = *(const float4*)(mr + 36);
        float iv[16];
        #pragma unroll
        for (int i = 0; i < 16; ++i) iv[i] = 1.0f / vv[i];
        U8 h0, h1, h2, h3;
        #pragma unroll
        for (int i = 0; i < 4; ++i) {
            h0.u[i] = f2bf2(-0.5f * iv[2*i],     -0.5f * iv[2*i + 1]);
            h1.u[i] = f2bf2(-0.5f * iv[8 + 2*i], -0.5f * iv[8 + 2*i + 1]);
            h2.u[i] = f2bf2(mm[2*i] * iv[2*i],   mm[2*i+1] * iv[2*i + 1]);
            h3.u[i] = f2bf2(mm[8+2*i] * iv[8+2*i], mm[8+2*i+1] * iv[8+2*i+1]);
        }
        short8* W = (short8*)wfS;
        W[(kt * 4 + 0) * 64 + lane] = h0.s8;
        W[(kt * 4 + 1) * 64 + lane] = h1.s8;
        W[(kt * 4 + 2) * 64 + lane] = h2.s8;
        W[(kt * 4 + 3) * 64 + lane] = h3.s8;
    }
    __syncthreads();            // red + wfS ready
    if ((t & 3) == 0) {
        int k = t >> 2;
        float sum = red[4 * k] + red[4 * k + 1] + red[4 * k + 2] + red[4 * k + 3];
        // D*log(2*pi) = 117.6241322501981
        c0s[k] = __logf(pi[k]) - 0.5f * (117.6241322502f + sum);
    }
    __syncthreads();            // c0s ready

    f32x4 c0v[4];
    #pragma unroll
    for (int kt = 0; kt < 4; ++kt)
        c0v[kt] = *(const f32x4*)&c0s[16 * kt + 4 * q];

    // ==================== main phase (R13 body, verbatim) ====================
    const int bi    = blockIdx.y;
    const int chunk = blockIdx.x;
    const int ppb   = N_ / CHUNKS;
    const float* xb = x + ((size_t)bi * N_ + (size_t)chunk * ppb) * D_;

    f32x4 accX[4]  = {};       // Qx  : k rows, d col = 16w + r16
    f32x4 accX2[4] = {};       // Qx2
    float qsacc[4][4] = {};    // per-lane Q sums (ks: 16kt + 4q + rr)

    const int rowoff = (16 * w + r16) * D_ + 8 * q;   // phase-1 row base
    const int dcol   = 16 * w + r16;                  // phase-2 column

    const short8* wfp = (const short8*)wfS;   // [(kt*4+op)*64 + lane]

    #pragma unroll 1
    for (int tile = 0; tile < NTILES; ++tile) {
        const float* xt = xb + (size_t)tile * 64 * D_;

        // ---- row loads for CURRENT tile ----
        float4 va, vb, vc, vd;
        {
            const float* xr = xt + rowoff;
            va = *(const float4*)(xr);
            vb = *(const float4*)(xr + 4);
            vc = *(const float4*)(xr + 32);
            vd = *(const float4*)(xr + 36);
        }

        // ================= phase 1: S^T[k][p] =================
        U8 fxa, fxb, fx2a, fx2b;
        fxa.u[0]  = f2bf2(va.x, va.y);           fxa.u[1]  = f2bf2(va.z, va.w);
        fxa.u[2]  = f2bf2(vb.x, vb.y);           fxa.u[3]  = f2bf2(vb.z, vb.w);
        fxb.u[0]  = f2bf2(vc.x, vc.y);           fxb.u[1]  = f2bf2(vc.z, vc.w);
        fxb.u[2]  = f2bf2(vd.x, vd.y);           fxb.u[3]  = f2bf2(vd.z, vd.w);
        fx2a.u[0] = f2bf2(va.x*va.x, va.y*va.y); fx2a.u[1] = f2bf2(va.z*va.z, va.w*va.w);
        fx2a.u[2] = f2bf2(vb.x*vb.x, vb.y*vb.y); fx2a.u[3] = f2bf2(vb.z*vb.z, vb.w*vb.w);
        fx2b.u[0] = f2bf2(vc.x*vc.x, vc.y*vc.y); fx2b.u[1] = f2bf2(vc.z*vc.z, vc.w*vc.w);
        fx2b.u[2] = f2bf2(vd.x*vd.x, vd.y*vd.y); fx2b.u[3] = f2bf2(vd.z*vd.z, vd.w*vd.w);

        float sc[4][4];
        #pragma unroll
        for (int kt = 0; kt < 4; ++kt) {
            f32x4 a = c0v[kt];
            a = __builtin_amdgcn_mfma_f32_16x16x32_bf16(wfp[(kt*4+0)*64 + lane], fx2a.s8, a, 0, 0, 0);
            a = __builtin_amdgcn_mfma_f32_16x16x32_bf16(wfp[(kt*4+1)*64 + lane], fx2b.s8, a, 0, 0, 0);
            a = __builtin_amdgcn_mfma_f32_16x16x32_bf16(wfp[(kt*4+2)*64 + lane], fxa.s8,  a, 0, 0, 0);
            a = __builtin_amdgcn_mfma_f32_16x16x32_bf16(wfp[(kt*4+3)*64 + lane], fxb.s8,  a, 0, 0, 0);
            sc[kt][0] = a[0]; sc[kt][1] = a[1]; sc[kt][2] = a[2]; sc[kt][3] = a[3];
        }

        // ---- softmax over k ----
        float mx = sc[0][0];
        #pragma unroll
        for (int kt = 0; kt < 4; ++kt)
            #pragma unroll
            for (int rr = 0; rr < 4; ++rr) mx = fmaxf(mx, sc[kt][rr]);
        mx = fmaxf(mx, __shfl_xor(mx, 16));
        mx = fmaxf(mx, __shfl_xor(mx, 32));
        float z = 0.0f;
        #pragma unroll
        for (int kt = 0; kt < 4; ++kt)
            #pragma unroll
            for (int rr = 0; rr < 4; ++rr) {
                sc[kt][rr] = __expf(sc[kt][rr] - mx);
                z += sc[kt][rr];
            }
        z += __shfl_xor(z, 16);
        z += __shfl_xor(z, 32);
        float inv = 1.0f / z;

        // ---- phase-2 column loads (post-softmax; in flight across barrier) ----
        float vle[16];
        {
            const float* xc = xt + dcol;
            #pragma unroll
            for (int c = 0; c < 2; ++c)
                #pragma unroll
                for (int j = 0; j < 8; ++j)
                    vle[8 * c + j] = xc[(32 * c + 8 * q + j) * D_];
        }

        const int p = 16 * w + r16;
        unsigned short* Qb = QtS[tile & 1];
        #pragma unroll
        for (int kt = 0; kt < 4; ++kt) {
            #pragma unroll
            for (int rr = 0; rr < 4; rr += 2) {
                float q0 = sc[kt][rr] * inv;
                float q1 = sc[kt][rr + 1] * inv;
                qsacc[kt][rr]     += q0;
                qsacc[kt][rr + 1] += q1;
                unsigned int pk = f2bf2(q0, q1);
                Qb[(16 * kt + 4 * q + rr)     * 72 + p] = (unsigned short)pk;
                Qb[(16 * kt + 4 * q + rr + 1) * 72 + p] = (unsigned short)(pk >> 16);
            }
        }

        // barrier WITHOUT vmcnt(0) drain (LDS visibility only)
        asm volatile("s_waitcnt lgkmcnt(0)\n\ts_barrier" ::: "memory");

        // ================= phase 2: Qx[k][d], Qx2[k][d] =================
        U8 fxp0, fxp1, fx2p0, fx2p1;
        #pragma unroll
        for (int i = 0; i < 4; ++i) {
            float a0 = vle[2 * i], a1 = vle[2 * i + 1];
            float b0 = vle[8 + 2 * i], b1 = vle[8 + 2 * i + 1];
            fxp0.u[i]  = f2bf2(a0, a1);
            fxp1.u[i]  = f2bf2(b0, b1);
            fx2p0.u[i] = f2bf2(a0 * a0, a1 * a1);
            fx2p1.u[i] = f2bf2(b0 * b0, b1 * b1);
        }
        #pragma unroll
        for (int kt = 0; kt < 4; ++kt) {
            const unsigned short* qr = &Qb[(16 * kt + r16) * 72 + 8 * q];
            short8 aq0 = *(const short8*)(const void*)(qr);
            short8 aq1 = *(const short8*)(const void*)(qr + 32);
            accX[kt]  = __builtin_amdgcn_mfma_f32_16x16x32_bf16(aq0, fxp0.s8,  accX[kt],  0, 0, 0);
            accX2[kt] = __builtin_amdgcn_mfma_f32_16x16x32_bf16(aq0, fx2p0.s8, accX2[kt], 0, 0, 0);
            accX[kt]  = __builtin_amdgcn_mfma_f32_16x16x32_bf16(aq1, fxp1.s8,  accX[kt],  0, 0, 0);
            accX2[kt] = __builtin_amdgcn_mfma_f32_16x16x32_bf16(aq1, fx2p1.s8, accX2[kt], 0, 0, 0);
        }
    }

    // ---- write partials: f32 qsum[64] | bf16 qx[4096] | bf16 qx2[4096] ----
    char* rec = partials + ((size_t)bi * CHUNKS + chunk) * PART_STRIDE;
    float* part_qs = (float*)rec;
    unsigned short* part_qx  = (unsigned short*)(rec + 256);
    unsigned short* part_qx2 = part_qx + 4096;
    #pragma unroll
    for (int kt = 0; kt < 4; ++kt)
        #pragma unroll
        for (int rr = 0; rr < 4; ++rr) {
            int k = 16 * kt + 4 * q + rr;
            part_qx [k * 64 + 16 * w + r16] = f2bf(accX[kt][rr]);
            part_qx2[k * 64 + 16 * w + r16] = f2bf(accX2[kt][rr]);
        }
    #pragma unroll
    for (int kt = 0; kt < 4; ++kt)
        #pragma unroll
        for (int rr = 0; rr < 4; ++rr) {
            float v = qsacc[kt][rr];
            v += __shfl_xor(v, 1);
            v += __shfl_xor(v, 2);
            v += __shfl_xor(v, 4);
            v += __shfl_xor(v, 8);
            if (r16 == 0) qsum_s[w][16 * kt + 4 * q + rr] = v;
        }
    __syncthreads();
    if (t < 64)
        part_qs[t] = qsum_s[0][t] + qsum_s[1][t] + qsum_s[2][t] + qsum_s[3][t];

    // ==================== grid-wide sync ====================
    __threadfence();            // release partials device-wide
    cg::this_grid().sync();
    __threadfence();            // acquire

    // ==================== finalize phase (R14 body; block = (b,k)) ====================
    {
        const int b    = blockIdx.y;
        const int k    = blockIdx.x;
        const int cgp  = t >> 6;          // wave: chunk-group of 16
        const int cs   = lane >> 3;       // chunk-sub 0..7
        const int dg   = lane & 7;        // d-octet 0..7

        const char* base = partials + (size_t)b * CHUNKS * PART_STRIDE;

        float qx[8]  = {};
        float qx2[8] = {};
        float qs = 0.0f;
        #pragma unroll
        for (int i = 0; i < 2; ++i) {
            const char* r = base + (size_t)(16 * cgp + 8 * i + cs) * PART_STRIDE;
            short8 vx  = *(const short8*)(const void*)(r + 256 + k * 128 + dg * 16);
            short8 vx2 = *(const short8*)(const void*)(r + 256 + 8192 + k * 128 + dg * 16);
            if (dg == 0) qs += ((const float*)r)[k];
            #pragma unroll
            for (int j = 0; j < 8; ++j) {
                qx[j]  += bf2f((unsigned short)vx[j]);
                qx2[j] += bf2f((unsigned short)vx2[j]);
            }
        }

        #pragma unroll
        for (int m = 8; m <= 32; m <<= 1) {
            #pragma unroll
            for (int j = 0; j < 8; ++j) {
                qx[j]  += __shfl_xor(qx[j],  m);
                qx2[j] += __shfl_xor(qx2[j], m);
            }
        }
        qs += __shfl_xor(qs, 1);
        qs += __shfl_xor(qs, 2);
        qs += __shfl_xor(qs, 4);
        qs += __shfl_xor(qs, 8);
        qs += __shfl_xor(qs, 16);
        qs += __shfl_xor(qs, 32);

        // LDS reuse: sQx = qsum_s, sQx2 = red, sQs = c0s (all dead post-gridsync)
        float (*sQx)[64]  = qsum_s;
        float (*sQx2)[64] = (float (*)[64])red;
        float* sQs = c0s;
        if (cs == 0) {
            #pragma unroll
            for (int j = 0; j < 8; ++j) {
                sQx[cgp][dg * 8 + j]  = qx[j];
                sQx2[cgp][dg * 8 + j] = qx2[j];
            }
        }
        if (lane == 0) sQs[cgp] = qs;
        __syncthreads();

        if (cgp == 0) {
            const int d = lane;           // 64 lanes cover d = 0..63
            const float invN = 1.0f / (float)N_;
            float QX  = sQx[0][d]  + sQx[1][d]  + sQx[2][d]  + sQx[3][d];
            float QX2 = sQx2[0][d] + sQx2[1][d] + sQx2[2][d] + sQx2[3][d];
            float QS  = sQs[0] + sQs[1] + sQs[2] + sQs[3];
            float m = mu[k * 64 + d];
            float v = var[k * 64 + d];
            float* ob = out + (size_t)b * OUT_PER_B;
            if (d == 0) ob[k] = QS * invN - pi[k];
            ob[64 + k * 64 + d]        = (QX - QS * m) * invN;
            ob[64 + 4096 + k * 64 + d] = (-QX2 - QS * m * m + QS * v + 2.0f * QX * m) * invN;
        }
    }
}

// ============================================================================
// Fallback path (R13/R14 kernels, verbatim) — used only if the cooperative
// launch cannot run at 4 blocks/CU co-residency.
// ============================================================================
__global__ __launch_bounds__(256) void fv_prep(const float* __restrict__ pi,
                                               const float* __restrict__ mu,
                                               const float* __restrict__ var,
                                               char* __restrict__ ws) {
    __shared__ float red[256];
    const int t = threadIdx.x;
    {
        int k = t >> 2, pr = t & 3;
        float s = 0.0f;
        #pragma unroll
        for (int j = 0; j < 16; ++j) {
            int d = pr * 16 + j;
            float v = var[k * 64 + d];
            float m = mu[k * 64 + d];
            s += __logf(v) + m * m / v;
        }
        red[t] = s;
    }
    {
        const int lane = t & 63;
        const int kt   = t >> 6;
        const int r16  = lane & 15;
        const int q    = lane >> 4;
        const int k = 16 * kt + r16;
        const float* vr = var + k * 64 + 8 * q;
        const float* mr = mu  + k * 64 + 8 * q;
        float vv[16], mm[16];
        *(float4*)&vv[0]  = *(const float4*)(vr);
        *(float4*)&vv[4]  = *(const float4*)(vr + 4);
        *(float4*)&vv[8]  = *(const float4*)(vr + 32);
        *(float4*)&vv[12] = *(const float4*)(vr + 36);
        *(float4*)&mm[0]  = *(const float4*)(mr);
        *(float4*)&mm[4]  = *(const float4*)(mr + 4);
        *(float4*)&mm[8]  = *(const float4*)(mr + 32);
        *(float4*)&mm[12] = *(const float4*)(mr + 36);
        float iv[16];
        #pragma unroll
        for (int i = 0; i < 16; ++i) iv[i] = 1.0f / vv[i];
        U8 h0, h1, h2, h3;
        #pragma unroll
        for (int i = 0; i < 4; ++i) {
            h0.u[i] = f2bf2(-0.5f * iv[2*i],     -0.5f * iv[2*i + 1]);
            h1.u[i] = f2bf2(-0.5f * iv[8 + 2*i], -0.5f * iv[8 + 2*i + 1]);
            h2.u[i] = f2bf2(mm[2*i] * iv[2*i],   mm[2*i+1] * iv[2*i + 1]);
            h3.u[i] = f2bf2(mm[8+2*i] * iv[8+2*i], mm[8+2*i+1] * iv[8+2*i+1]);
        }
        short8* W = (short8*)(ws + W_OFF);
        W[(kt * 4 + 0) * 64 + lane] = h0.s8;
        W[(kt * 4 + 1) * 64 + lane] = h1.s8;
        W[(kt * 4 + 2) * 64 + lane] = h2.s8;
        W[(kt * 4 + 3) * 64 + lane] = h3.s8;
    }
    __syncthreads();
    if ((t & 3) == 0) {
        int k = t >> 2;
        float sum = red[4 * k] + red[4 * k + 1] + red[4 * k + 2] + red[4 * k + 3];
        ((float*)(ws + C0_OFF))[k] = __logf(pi[k]) - 0.5f * (117.6241322502f + sum);
    }
}

__global__ __launch_bounds__(256, 4) void fv_main(const float* __restrict__ x,
                                                  char* __restrict__ partials) {
    __shared__ __align__(16) unsigned short QtS[2][64 * 72];
    __shared__ __align__(16) unsigned short wfS[4 * 4 * 64 * 8];
    __shared__ float qsum_s[4][64];

    const int t    = threadIdx.x;
    const int w    = t >> 6;
    const int lane = t & 63;
    const int r16  = lane & 15;
    const int q    = lane >> 4;

    {
        const float4* gw = (const float4*)(partials + W_OFF);
        float4* sw = (float4*)wfS;
        #pragma unroll
        for (int i = 0; i < 4; ++i) sw[i * 256 + t] = gw[i * 256 + t];
    }
    f32x4 c0v[4];
    {
        const float* c0g = (const float*)(partials + C0_OFF);
        #pragma unroll
        for (int kt = 0; kt < 4; ++kt)
            c0v[kt] = *(const f32x4*)&c0g[16 * kt + 4 * q];
    }

    const int bi    = blockIdx.y;
    const int chunk = blockIdx.x;
    const int ppb   = N_ / CHUNKS;
    const float* xb = x + ((size_t)bi * N_ + (size_t)chunk * ppb) * D_;

    f32x4 accX[4]  = {};
    f32x4 accX2[4] = {};
    float qsacc[4][4] = {};

    const int rowoff = (16 * w + r16) * D_ + 8 * q;
    const int dcol   = 16 * w + r16;

    const short8* wfp = (const short8*)wfS;

    __syncthreads();

    #pragma unroll 1
    for (int tile = 0; tile < NTILES; ++tile) {
        const float* xt = xb + (size_t)tile * 64 * D_;
        float4 va, vb, vc, vd;
        {
            const float* xr = xt + rowoff;
            va = *(const float4*)(xr);
            vb = *(const float4*)(xr + 4);
            vc = *(const float4*)(xr + 32);
            vd = *(const float4*)(xr + 36);
        }
        U8 fxa, fxb, fx2a, fx2b;
        fxa.u[0]  = f2bf2(va.x, va.y);           fxa.u[1]  = f2bf2(va.z, va.w);
        fxa.u[2]  = f2bf2(vb.x, vb.y);           fxa.u[3]  = f2bf2(vb.z, vb.w);
        fxb.u[0]  = f2bf2(vc.x, vc.y);           fxb.u[1]  = f2bf2(vc.z, vc.w);
        fxb.u[2]  = f2bf2(vd.x, vd.y);           fxb.u[3]  = f2bf2(vd.z, vd.w);
        fx2a.u[0] = f2bf2(va.x*va.x, va.y*va.y); fx2a.u[1] = f2bf2(va.z*va.z, va.w*va.w);
        fx2a.u[2] = f2bf2(vb.x*vb.x, vb.y*vb.y); fx2a.u[3] = f2bf2(vb.z*vb.z, vb.w*vb.w);
        fx2b.u[0] = f2bf2(vc.x*vc.x, vc.y*vc.y); fx2b.u[1] = f2bf2(vc.z*vc.z, vc.w*vc.w);
        fx2b.u[2] = f2bf2(vd.x*vd.x, vd.y*vd.y); fx2b.u[3] = f2bf2(vd.z*vd.z, vd.w*vd.w);

        float sc[4][4];
        #pragma unroll
        for (int kt = 0; kt < 4; ++kt) {
            f32x4 a = c0v[kt];
            a = __builtin_amdgcn_mfma_f32_16x16x32_bf16(wfp[(kt*4+0)*64 + lane], fx2a.s8, a, 0, 0, 0);
            a = __builtin_amdgcn_mfma_f32_16x16x32_bf16(wfp[(kt*4+1)*64 + lane], fx2b.s8, a, 0, 0, 0);
            a = __builtin_amdgcn_mfma_f32_16x16x32_bf16(wfp[(kt*4+2)*64 + lane], fxa.s8,  a, 0, 0, 0);
            a = __builtin_amdgcn_mfma_f32_16x16x32_bf16(wfp[(kt*4+3)*64 + lane], fxb.s8,  a, 0, 0, 0);
            sc[kt][0] = a[0]; sc[kt][1] = a[1]; sc[kt][2] = a[2]; sc[kt][3] = a[3];
        }

        float mx = sc[0][0];
        #pragma unroll
        for (int kt = 0; kt < 4; ++kt)
            #pragma unroll
            for (int rr = 0; rr < 4; ++rr) mx = fmaxf(mx, sc[kt][rr]);
        mx = fmaxf(mx, __shfl_xor(mx, 16));
        mx = fmaxf(mx, __shfl_xor(mx, 32));
        float z = 0.0f;
        #pragma unroll
        for (int kt = 0; kt < 4; ++kt)
            #pragma unroll
            for (int rr = 0; rr < 4; ++rr) {
                sc[kt][rr] = __expf(sc[kt][rr] - mx);
                z += sc[kt][rr];
            }
        z += __shfl_xor(z, 16);
        z += __shfl_xor(z, 32);
        float inv = 1.0f / z;

        float vle[16];
        {
            const float* xc = xt + dcol;
            #pragma unroll
            for (int c = 0; c < 2; ++c)
                #pragma unroll
                for (int j = 0; j < 8; ++j)
                    vle[8 * c + j] = xc[(32 * c + 8 * q + j) * D_];
        }

        const int p = 16 * w + r16;
        unsigned short* Qb = QtS[tile & 1];
        #pragma unroll
        for (int kt = 0; kt < 4; ++kt) {
            #pragma unroll
            for (int rr = 0; rr < 4; rr += 2) {
                float q0 = sc[kt][rr] * inv;
                float q1 = sc[kt][rr + 1] * inv;
                qsacc[kt][rr]     += q0;
                qsacc[kt][rr + 1] += q1;
                unsigned int pk = f2bf2(q0, q1);
                Qb[(16 * kt + 4 * q + rr)     * 72 + p] = (unsigned short)pk;
                Qb[(16 * kt + 4 * q + rr + 1) * 72 + p] = (unsigned short)(pk >> 16);
            }
        }

        asm volatile("s_waitcnt lgkmcnt(0)\n\ts_barrier" ::: "memory");

        U8 fxp0, fxp1, fx2p0, fx2p1;
        #pragma unroll
        for (int i = 0; i < 4; ++i) {
            float a0 = vle[2 * i], a1 = vle[2 * i + 1];
            float b0 = vle[8 + 2 * i], b1 = vle[8 + 2 * i + 1];
            fxp0.u[i]  = f2bf2(a0, a1);
            fxp1.u[i]  = f2bf2(b0, b1);
            fx2p0.u[i] = f2bf2(a0 * a0, a1 * a1);
            fx2p1.u[i] = f2bf2(b0 * b0, b1 * b1);
        }
        #pragma unroll
        for (int kt = 0; kt < 4; ++kt) {
            const unsigned short* qr = &Qb[(16 * kt + r16) * 72 + 8 * q];
            short8 aq0 = *(const short8*)(const void*)(qr);
            short8 aq1 = *(const short8*)(const void*)(qr + 32);
            accX[kt]  = __builtin_amdgcn_mfma_f32_16x16x32_bf16(aq0, fxp0.s8,  accX[kt],  0, 0, 0);
            accX2[kt] = __builtin_amdgcn_mfma_f32_16x16x32_bf16(aq0, fx2p0.s8, accX2[kt], 0, 0, 0);
            accX[kt]  = __builtin_amdgcn_mfma_f32_16x16x32_bf16(aq1, fxp1.s8,  accX[kt],  0, 0, 0);
            accX2[kt] = __builtin_amdgcn_mfma_f32_16x16x32_bf16(aq1, fx2p1.s8, accX2[kt], 0, 0, 0);
        }
    }

    char* rec = partials + ((size_t)bi * CHUNKS + chunk) * PART_STRIDE;
    float* part_qs = (float*)rec;
    unsigned short* part_qx  = (unsigned short*)(rec + 256);
    unsigned short* part_qx2 = part_qx + 4096;
    #pragma unroll
    for (int kt = 0; kt < 4; ++kt)
        #pragma unroll
        for (int rr = 0; rr < 4; ++rr) {
            int k = 16 * kt + 4 * q + rr;
            part_qx [k * 64 + 16 * w + r16] = f2bf(accX[kt][rr]);
            part_qx2[k * 64 + 16 * w + r16] = f2bf(accX2[kt][rr]);
        }
    #pragma unroll
    for (int kt = 0; kt < 4; ++kt)
        #pragma unroll
        for (int rr = 0; rr < 4; ++rr) {
            float v = qsacc[kt][rr];
            v += __shfl_xor(v, 1);
            v += __shfl_xor(v, 2);
            v += __shfl_xor(v, 4);
            v += __shfl_xor(v, 8);
            if (r16 == 0) qsum_s[w][16 * kt + 4 * q + rr] = v;
        }
    __syncthreads();
    if (t < 64)
        part_qs[t] = qsum_s[0][t] + qsum_s[1][t] + qsum_s[2][t] + qsum_s[3][t];
}

__global__ __launch_bounds__(256) void fv_finalize(const float* __restrict__ pi,
                                                   const float* __restrict__ mu,
                                                   const float* __restrict__ var,
                                                   const char* __restrict__ partials,
                                                   float* __restrict__ out) {
    const int bk   = blockIdx.x;
    const int b    = bk >> 6;
    const int k    = bk & 63;
    const int t    = threadIdx.x;
    const int cgp  = t >> 6;
    const int lane = t & 63;
    const int cs   = lane >> 3;
    const int dg   = lane & 7;

    const char* base = partials + (size_t)b * CHUNKS * PART_STRIDE;

    float qx[8]  = {};
    float qx2[8] = {};
    float qs = 0.0f;
    #pragma unroll
    for (int i = 0; i < 2; ++i) {
        const char* r = base + (size_t)(16 * cgp + 8 * i + cs) * PART_STRIDE;
        short8 vx  = *(const short8*)(const void*)(r + 256 + k * 128 + dg * 16);
        short8 vx2 = *(const short8*)(const void*)(r + 256 + 8192 + k * 128 + dg * 16);
        if (dg == 0) qs += ((const float*)r)[k];
        #pragma unroll
        for (int j = 0; j < 8; ++j) {
            qx[j]  += bf2f((unsigned short)vx[j]);
            qx2[j] += bf2f((unsigned short)vx2[j]);
        }
    }
    #pragma unroll
    for (int m = 8; m <= 32; m <<= 1) {
        #pragma unroll
        for (int j = 0; j < 8; ++j) {
            qx[j]  += __shfl_xor(qx[j],  m);
            qx2[j] += __shfl_xor(qx2[j], m);
        }
    }
    qs += __shfl_xor(qs, 1);
    qs += __shfl_xor(qs, 2);
    qs += __shfl_xor(qs, 4);
    qs += __shfl_xor(qs, 8);
    qs += __shfl_xor(qs, 16);
    qs += __shfl_xor(qs, 32);

    __shared__ float sQx[4][64];
    __shared__ float sQx2[4][64];
    __shared__ float sQs[4];
    if (cs == 0) {
        #pragma unroll
        for (int j = 0; j < 8; ++j) {
            sQx[cgp][dg * 8 + j]  = qx[j];
            sQx2[cgp][dg * 8 + j] = qx2[j];
        }
    }
    if (lane == 0) sQs[cgp] = qs;
    __syncthreads();

    if (cgp == 0) {
        const int d = lane;
        const float invN = 1.0f / (float)N_;
        float QX  = sQx[0][d]  + sQx[1][d]  + sQx[2][d]  + sQx[3][d];
        float QX2 = sQx2[0][d] + sQx2[1][d] + sQx2[2][d] + sQx2[3][d];
        float QS  = sQs[0] + sQs[1] + sQs[2] + sQs[3];
        float m = mu[k * 64 + d];
        float v = var[k * 64 + d];
        float* ob = out + (size_t)b * OUT_PER_B;
        if (d == 0) ob[k] = QS * invN - pi[k];
        ob[64 + k * 64 + d]        = (QX - QS * m) * invN;
        ob[64 + 4096 + k * 64 + d] = (-QX2 - QS * m * m + QS * v + 2.0f * QX * m) * invN;
    }
}

extern "C" void kernel_launch(void* const* d_in, const int* in_sizes, int n_in,
                              void* d_out, int out_size, void* d_ws, size_t ws_size,
                              hipStream_t stream) {
    const float* x   = (const float*)d_in[0];
    const float* pi  = (const float*)d_in[1];
    const float* mu  = (const float*)d_in[2];
    const float* var = (const float*)d_in[3];
    char* ws = (char*)d_ws;
    float* outp = (float*)d_out;

    // One-time co-residency check for the cooperative single-kernel path.
    static int use_coop = -1;
    if (use_coop < 0) {
        int maxb = 0;
        hipError_t e = hipOccupancyMaxActiveBlocksPerMultiprocessor(
            &maxb, (const void*)fv_fused, 256, 0);
        use_coop = (e == hipSuccess && maxb >= 4) ? 1 : 0;
    }

    if (use_coop) {
        void* args[] = {(void*)&x, (void*)&pi, (void*)&mu, (void*)&var,
                        (void*)&ws, (void*)&outp};
        hipError_t e = hipLaunchCooperativeKernel(
            (const void*)fv_fused, dim3(CHUNKS, B_), dim3(256), args, 0, stream);
        if (e == hipSuccess) return;
        use_coop = 0;   // launch refused -> permanent fallback
    }

    fv_prep<<<1, 256, 0, stream>>>(pi, mu, var, ws);
    fv_main<<<dim3(CHUNKS, B_), 256, 0, stream>>>(x, ws);
    fv_finalize<<<B_ * K_, 256, 0, stream>>>(pi, mu, var, ws, outp);
}

// Round 9
// 119.825 us; speedup vs baseline: 1.0070x; 1.0002x over previous
//
#include <hip/hip_runtime.h>
#include <hip/hip_bf16.h>
#include <math.h>

// Problem constants (fixed by the reference).
#define B_  16
#define N_  16384
#define D_  64
#define K_  64
#define OUT_PER_B (K_ + 2*K_*D_)   // 8256
#define CHUNKS 64                  // 1024 blocks = EXACTLY 4 blocks/CU x 256 CU
#define NTILES (N_ / CHUNKS / 64)  // 4

// ws layout: per (b,chunk) partial record at offset (b*CHUNKS+chunk)*PART_STRIDE:
//   f32 qsum[64] | bf16 qx[64*64] | bf16 qx2[64*64]   (16640 B)
#define PART_STRIDE (64*4 + 2*4096*2)   // 16640 bytes
#define PART_TOTAL  ((size_t)B_ * CHUNKS * PART_STRIDE)   // 17,039,360 B
// prep region appended after partials:
#define W_OFF   PART_TOTAL            // 16 KB packed wfrag [(kt*4+op)*64+lane]*16B
#define C0_OFF  (PART_TOTAL + 16384)  // 64 f32

typedef float f32x4 __attribute__((ext_vector_type(4)));
typedef short short8 __attribute__((ext_vector_type(8)));

union U8 { short8 s8; unsigned int u[4]; };

__device__ __forceinline__ unsigned short f2bf(float f) {
    union { float f; unsigned int u; } v; v.f = f;
    unsigned int r = v.u + 0x7FFFu + ((v.u >> 16) & 1u);   // round-to-nearest-even
    return (unsigned short)(r >> 16);
}

// packed RNE f32x2 -> bf16x2 (v_cvt_pk_bf16_f32 on gfx950)
__device__ __forceinline__ unsigned int f2bf2(float lo, float hi) {
    __hip_bfloat162 h = __float22bfloat162_rn(make_float2(lo, hi));
    unsigned int u;
    __builtin_memcpy(&u, &h, 4);
    return u;
}

__device__ __forceinline__ float bf2f(unsigned short u) {
    unsigned int v = ((unsigned int)u) << 16;
    float f;
    __builtin_memcpy(&f, &v, 4);
    return f;
}

// Prep (R11): wfrag depends only on lane -> compute ONCE (16 KB) + c0s, to ws.
__global__ __launch_bounds__(256) void fv_prep(const float* __restrict__ pi,
                                               const float* __restrict__ mu,
                                               const float* __restrict__ var,
                                               char* __restrict__ ws) {
    __shared__ float red[256];
    const int t = threadIdx.x;

    // c0 partial sums (exact replication of original summation order)
    {
        int k = t >> 2, pr = t & 3;
        float s = 0.0f;
        #pragma unroll
        for (int j = 0; j < 16; ++j) {
            int d = pr * 16 + j;
            float v = var[k * 64 + d];
            float m = mu[k * 64 + d];
            s += __logf(v) + m * m / v;
        }
        red[t] = s;
    }

    // wfrag for (lane = t&63, kt = t>>6)
    {
        const int lane = t & 63;
        const int kt   = t >> 6;
        const int r16  = lane & 15;
        const int q    = lane >> 4;
        const int k = 16 * kt + r16;
        const float* vr = var + k * 64 + 8 * q;
        const float* mr = mu  + k * 64 + 8 * q;
        float vv[16], mm[16];
        *(float4*)&vv[0]  = *(const float4*)(vr);
        *(float4*)&vv[4]  = *(const float4*)(vr + 4);
        *(float4*)&vv[8]  = *(const float4*)(vr + 32);
        *(float4*)&vv[12] = *(const float4*)(vr + 36);
        *(float4*)&mm[0]  = *(const float4*)(mr);
        *(float4*)&mm[4]  = *(const float4*)(mr + 4);
        *(float4*)&mm[8]  = *(const float4*)(mr + 32);
        *(float4*)&mm[12] = *(const float4*)(mr + 36);
        float iv[16];
        #pragma unroll
        for (int i = 0; i < 16; ++i) iv[i] = 1.0f / vv[i];
        U8 h0, h1, h2, h3;
        #pragma unroll
        for (int i = 0; i < 4; ++i) {
            h0.u[i] = f2bf2(-0.5f * iv[2*i],     -0.5f * iv[2*i + 1]);
            h1.u[i] = f2bf2(-0.5f * iv[8 + 2*i], -0.5f * iv[8 + 2*i + 1]);
            h2.u[i] = f2bf2(mm[2*i] * iv[2*i],   mm[2*i+1] * iv[2*i + 1]);
            h3.u[i] = f2bf2(mm[8+2*i] * iv[8+2*i], mm[8+2*i+1] * iv[8+2*i+1]);
        }
        short8* W = (short8*)(ws + W_OFF);
        W[(kt * 4 + 0) * 64 + lane] = h0.s8;
        W[(kt * 4 + 1) * 64 + lane] = h1.s8;
        W[(kt * 4 + 2) * 64 + lane] = h2.s8;
        W[(kt * 4 + 3) * 64 + lane] = h3.s8;
    }

    __syncthreads();
    if ((t & 3) == 0) {
        int k = t >> 2;
        float sum = red[4 * k] + red[4 * k + 1] + red[4 * k + 2] + red[4 * k + 3];
        // D*log(2*pi) = 117.6241322501981
        ((float*)(ws + C0_OFF))[k] = __logf(pi[k]) - 0.5f * (117.6241322502f + sum);
    }
}

// MFMA layouts (16x16x32 bf16, guide-verified):
//   A[m = lane&15][kk = (lane>>4)*8 + j]
//   B[kk = (lane>>4)*8 + j][n = lane&15]
//   C/D: col = lane&15, row = 4*(lane>>4) + reg
// R16: restore next-tile row prefetch at 4 blocks/CU, register-neutrally:
//  - rows are converted to bf16 fragments at TILE TOP, then va..vd are REUSED
//    as the prefetch destination for tile+1 (longer live range, no new regs)
//  - c0 moved from 16 VGPRs to LDS (4 ds_read_b128/tile, lgkm-covered)
// vle stays post-softmax (R13). (256,4) kept: 1024 blocks = one packed round.
// Guard: FETCH ~33-40 MB / WRITE ~17 MB. Inflation = spill -> revert.
__global__ __launch_bounds__(256, 4) void fv_main(const float* __restrict__ x,
                                                  char* __restrict__ partials) {
    __shared__ __align__(16) unsigned short QtS[2][64 * 72];      // 18432 B
    __shared__ __align__(16) unsigned short wfS[4 * 4 * 64 * 8];  // 16384 B
    __shared__ float qsum_s[4][64];
    __shared__ __align__(16) float c0sh[64];

    const int t    = threadIdx.x;
    const int w    = t >> 6;        // wave 0..3
    const int lane = t & 63;
    const int r16  = lane & 15;
    const int q    = lane >> 4;     // quad 0..3

    // ---- cooperative load of precomputed wfrag into LDS (16 KB, coalesced) ----
    {
        const float4* gw = (const float4*)(partials + W_OFF);
        float4* sw = (float4*)wfS;
        #pragma unroll
        for (int i = 0; i < 4; ++i) sw[i * 256 + t] = gw[i * 256 + t];
    }
    // c0 row constants -> LDS (256 B); read per-tile as f32x4 (frees 16 VGPRs)
    if (t < 64) c0sh[t] = ((const float*)(partials + C0_OFF))[t];

    const int bi    = blockIdx.y;
    const int chunk = blockIdx.x;
    const int ppb   = N_ / CHUNKS;
    const float* xb = x + ((size_t)bi * N_ + (size_t)chunk * ppb) * D_;

    f32x4 accX[4]  = {};       // Qx  : k rows, d col = 16w + r16
    f32x4 accX2[4] = {};       // Qx2
    float qsacc[4][4] = {};    // per-lane Q sums (ks: 16kt + 4q + rr)

    const int rowoff = (16 * w + r16) * D_ + 8 * q;   // phase-1 row base
    const int dcol   = 16 * w + r16;                  // phase-2 column

    const short8* wfp = (const short8*)wfS;   // [(kt*4+op)*64 + lane]

    // ---- preload tile-0 rows ----
    float4 va, vb, vc, vd;
    {
        const float* xr = xb + rowoff;
        va = *(const float4*)(xr);
        vb = *(const float4*)(xr + 4);
        vc = *(const float4*)(xr + 32);
        vd = *(const float4*)(xr + 36);
    }

    __syncthreads();            // wfS + c0sh ready

    #pragma unroll 1
    for (int tile = 0; tile < NTILES; ++tile) {
        const float* xt = xb + (size_t)tile * 64 * D_;

        // ================= phase 1: convert rows first (frees va..vd) =========
        U8 fxa, fxb, fx2a, fx2b;
        fxa.u[0]  = f2bf2(va.x, va.y);           fxa.u[1]  = f2bf2(va.z, va.w);
        fxa.u[2]  = f2bf2(vb.x, vb.y);           fxa.u[3]  = f2bf2(vb.z, vb.w);
        fxb.u[0]  = f2bf2(vc.x, vc.y);           fxb.u[1]  = f2bf2(vc.z, vc.w);
        fxb.u[2]  = f2bf2(vd.x, vd.y);           fxb.u[3]  = f2bf2(vd.z, vd.w);
        fx2a.u[0] = f2bf2(va.x*va.x, va.y*va.y); fx2a.u[1] = f2bf2(va.z*va.z, va.w*va.w);
        fx2a.u[2] = f2bf2(vb.x*vb.x, vb.y*vb.y); fx2a.u[3] = f2bf2(vb.z*vb.z, vb.w*vb.w);
        fx2b.u[0] = f2bf2(vc.x*vc.x, vc.y*vc.y); fx2b.u[1] = f2bf2(vc.z*vc.z, vc.w*vc.w);
        fx2b.u[2] = f2bf2(vd.x*vd.x, vd.y*vd.y); fx2b.u[3] = f2bf2(vd.z*vd.z, vd.w*vd.w);

        // ---- prefetch NEXT tile's rows into the just-freed va..vd; these fly
        //      through MFMA + softmax + Q-write + barrier + phase 2 (~1500 cyc) ----
        if (tile + 1 < NTILES) {
            const float* xr = xt + 64 * D_ + rowoff;
            va = *(const float4*)(xr);
            vb = *(const float4*)(xr + 4);
            vc = *(const float4*)(xr + 32);
            vd = *(const float4*)(xr + 36);
        }

        float sc[4][4];
        #pragma unroll
        for (int kt = 0; kt < 4; ++kt) {
            f32x4 a = *(const f32x4*)&c0sh[16 * kt + 4 * q];
            a = __builtin_amdgcn_mfma_f32_16x16x32_bf16(wfp[(kt*4+0)*64 + lane], fx2a.s8, a, 0, 0, 0);
            a = __builtin_amdgcn_mfma_f32_16x16x32_bf16(wfp[(kt*4+1)*64 + lane], fx2b.s8, a, 0, 0, 0);
            a = __builtin_amdgcn_mfma_f32_16x16x32_bf16(wfp[(kt*4+2)*64 + lane], fxa.s8,  a, 0, 0, 0);
            a = __builtin_amdgcn_mfma_f32_16x16x32_bf16(wfp[(kt*4+3)*64 + lane], fxb.s8,  a, 0, 0, 0);
            sc[kt][0] = a[0]; sc[kt][1] = a[1]; sc[kt][2] = a[2]; sc[kt][3] = a[3];
        }

        // ---- softmax over k: 16 in-lane values + lanes^16,^32 (same point p) ----
        float mx = sc[0][0];
        #pragma unroll
        for (int kt = 0; kt < 4; ++kt)
            #pragma unroll
            for (int rr = 0; rr < 4; ++rr) mx = fmaxf(mx, sc[kt][rr]);
        mx = fmaxf(mx, __shfl_xor(mx, 16));
        mx = fmaxf(mx, __shfl_xor(mx, 32));
        float z = 0.0f;
        #pragma unroll
        for (int kt = 0; kt < 4; ++kt)
            #pragma unroll
            for (int rr = 0; rr < 4; ++rr) {
                sc[kt][rr] = __expf(sc[kt][rr] - mx);
                z += sc[kt][rr];
            }
        z += __shfl_xor(z, 16);
        z += __shfl_xor(z, 32);
        float inv = 1.0f / z;

        // ---- phase-2 column loads (post-softmax, short live range; stay
        //      vmcnt-in-flight across the lgkmcnt-only barrier) ----
        float vle[16];
        {
            const float* xc = xt + dcol;
            #pragma unroll
            for (int c = 0; c < 2; ++c)
                #pragma unroll
                for (int j = 0; j < 8; ++j)
                    vle[8 * c + j] = xc[(32 * c + 8 * q + j) * D_];
        }

        const int p = 16 * w + r16;
        unsigned short* Qb = QtS[tile & 1];
        #pragma unroll
        for (int kt = 0; kt < 4; ++kt) {
            #pragma unroll
            for (int rr = 0; rr < 4; rr += 2) {
                float q0 = sc[kt][rr] * inv;
                float q1 = sc[kt][rr + 1] * inv;
                qsacc[kt][rr]     += q0;
                qsacc[kt][rr + 1] += q1;
                unsigned int pk = f2bf2(q0, q1);
                Qb[(16 * kt + 4 * q + rr)     * 72 + p] = (unsigned short)pk;
                Qb[(16 * kt + 4 * q + rr + 1) * 72 + p] = (unsigned short)(pk >> 16);
            }
        }

        // barrier WITHOUT vmcnt(0) drain (LDS visibility only) — keeps the
        // row prefetch + vle loads in flight
        asm volatile("s_waitcnt lgkmcnt(0)\n\ts_barrier" ::: "memory");

        // ================= phase 2: Qx[k][d], Qx2[k][d] =================
        U8 fxp0, fxp1, fx2p0, fx2p1;
        #pragma unroll
        for (int i = 0; i < 4; ++i) {
            float a0 = vle[2 * i], a1 = vle[2 * i + 1];
            float b0 = vle[8 + 2 * i], b1 = vle[8 + 2 * i + 1];
            fxp0.u[i]  = f2bf2(a0, a1);
            fxp1.u[i]  = f2bf2(b0, b1);
            fx2p0.u[i] = f2bf2(a0 * a0, a1 * a1);
            fx2p1.u[i] = f2bf2(b0 * b0, b1 * b1);
        }
        #pragma unroll
        for (int kt = 0; kt < 4; ++kt) {
            const unsigned short* qr = &Qb[(16 * kt + r16) * 72 + 8 * q];
            short8 aq0 = *(const short8*)(const void*)(qr);
            short8 aq1 = *(const short8*)(const void*)(qr + 32);
            accX[kt]  = __builtin_amdgcn_mfma_f32_16x16x32_bf16(aq0, fxp0.s8,  accX[kt],  0, 0, 0);
            accX2[kt] = __builtin_amdgcn_mfma_f32_16x16x32_bf16(aq0, fx2p0.s8, accX2[kt], 0, 0, 0);
            accX[kt]  = __builtin_amdgcn_mfma_f32_16x16x32_bf16(aq1, fxp1.s8,  accX[kt],  0, 0, 0);
            accX2[kt] = __builtin_amdgcn_mfma_f32_16x16x32_bf16(aq1, fx2p1.s8, accX2[kt], 0, 0, 0);
        }
    }

    // ---- write partials: f32 qsum[64] | bf16 qx[4096] | bf16 qx2[4096] ----
    char* rec = partials + ((size_t)bi * CHUNKS + chunk) * PART_STRIDE;
    float* part_qs = (float*)rec;
    unsigned short* part_qx  = (unsigned short*)(rec + 256);
    unsigned short* part_qx2 = part_qx + 4096;
    #pragma unroll
    for (int kt = 0; kt < 4; ++kt)
        #pragma unroll
        for (int rr = 0; rr < 4; ++rr) {
            int k = 16 * kt + 4 * q + rr;
            part_qx [k * 64 + 16 * w + r16] = f2bf(accX[kt][rr]);
            part_qx2[k * 64 + 16 * w + r16] = f2bf(accX2[kt][rr]);
        }
    #pragma unroll
    for (int kt = 0; kt < 4; ++kt)
        #pragma unroll
        for (int rr = 0; rr < 4; ++rr) {
            float v = qsacc[kt][rr];
            v += __shfl_xor(v, 1);
            v += __shfl_xor(v, 2);
            v += __shfl_xor(v, 4);
            v += __shfl_xor(v, 8);
            if (r16 == 0) qsum_s[w][16 * kt + 4 * q + rr] = v;
        }
    __syncthreads();
    if (t < 64)
        part_qs[t] = qsum_s[0][t] + qsum_s[1][t] + qsum_s[2][t] + qsum_s[3][t];
}

// R14 finalize: vectorized + shuffle-tree. One block per (b,k); one short8
// load per lane covers 8 chunks x 128 B; cross-chunk reduce via shfl_xor.
__global__ __launch_bounds__(256) void fv_finalize(const float* __restrict__ pi,
                                                   const float* __restrict__ mu,
                                                   const float* __restrict__ var,
                                                   const char* __restrict__ partials,
                                                   float* __restrict__ out) {
    const int bk   = blockIdx.x;
    const int b    = bk >> 6;
    const int k    = bk & 63;
    const int t    = threadIdx.x;
    const int cg   = t >> 6;            // wave: chunk-group of 16
    const int lane = t & 63;
    const int cs   = lane >> 3;         // chunk-sub 0..7
    const int dg   = lane & 7;          // d-octet 0..7

    const char* base = partials + (size_t)b * CHUNKS * PART_STRIDE;

    float qx[8]  = {};
    float qx2[8] = {};
    float qs = 0.0f;
    #pragma unroll
    for (int i = 0; i < 2; ++i) {
        const char* r = base + (size_t)(16 * cg + 8 * i + cs) * PART_STRIDE;
        short8 vx  = *(const short8*)(const void*)(r + 256 + k * 128 + dg * 16);
        short8 vx2 = *(const short8*)(const void*)(r + 256 + 8192 + k * 128 + dg * 16);
        if (dg == 0) qs += ((const float*)r)[k];
        #pragma unroll
        for (int j = 0; j < 8; ++j) {
            qx[j]  += bf2f((unsigned short)vx[j]);
            qx2[j] += bf2f((unsigned short)vx2[j]);
        }
    }

    #pragma unroll
    for (int m = 8; m <= 32; m <<= 1) {
        #pragma unroll
        for (int j = 0; j < 8; ++j) {
            qx[j]  += __shfl_xor(qx[j],  m);
            qx2[j] += __shfl_xor(qx2[j], m);
        }
    }
    qs += __shfl_xor(qs, 1);
    qs += __shfl_xor(qs, 2);
    qs += __shfl_xor(qs, 4);
    qs += __shfl_xor(qs, 8);
    qs += __shfl_xor(qs, 16);
    qs += __shfl_xor(qs, 32);

    __shared__ float sQx[4][64];
    __shared__ float sQx2[4][64];
    __shared__ float sQs[4];
    if (cs == 0) {
        #pragma unroll
        for (int j = 0; j < 8; ++j) {
            sQx[cg][dg * 8 + j]  = qx[j];
            sQx2[cg][dg * 8 + j] = qx2[j];
        }
    }
    if (lane == 0) sQs[cg] = qs;
    __syncthreads();

    if (cg == 0) {
        const int d = lane;             // 64 lanes cover d = 0..63
        const float invN = 1.0f / (float)N_;
        float QX  = sQx[0][d]  + sQx[1][d]  + sQx[2][d]  + sQx[3][d];
        float QX2 = sQx2[0][d] + sQx2[1][d] + sQx2[2][d] + sQx2[3][d];
        float QS  = sQs[0] + sQs[1] + sQs[2] + sQs[3];
        float m = mu[k * 64 + d];
        float v = var[k * 64 + d];
        float* ob = out + (size_t)b * OUT_PER_B;
        if (d == 0) ob[k] = QS * invN - pi[k];
        ob[64 + k * 64 + d]        = (QX - QS * m) * invN;
        ob[64 + 4096 + k * 64 + d] = (-QX2 - QS * m * m + QS * v + 2.0f * QX * m) * invN;
    }
}

extern "C" void kernel_launch(void* const* d_in, const int* in_sizes, int n_in,
                              void* d_out, int out_size, void* d_ws, size_t ws_size,
                              hipStream_t stream) {
    const float* x   = (const float*)d_in[0];
    const float* pi  = (const float*)d_in[1];
    const float* mu  = (const float*)d_in[2];
    const float* var = (const float*)d_in[3];
    char* ws = (char*)d_ws;

    fv_prep<<<1, 256, 0, stream>>>(pi, mu, var, ws);
    fv_main<<<dim3(CHUNKS, B_), 256, 0, stream>>>(x, ws);
    fv_finalize<<<B_ * K_, 256, 0, stream>>>(pi, mu, var, ws, (float*)d_out);
}